// Round 2
// baseline (180.848 us; speedup 1.0000x reference)
//
#include <hip/hip_runtime.h>
#include <hip/hip_bf16.h>
#include <math.h>

// MultiHeadAttentionQuantum, B=2048 S=1 E=1024 H=128 DK=NW=8
// ALL inputs/outputs are float32 (per reference dtypes).
//
// Algebraic simplification:
//  - S==1 -> softmax over single key == 1 -> attention out == v = x @ Wv^T
//    (wq, wk are dead inputs)
//  - RX gates on one wire compose additively; CNOTs permute basis states
//    classically, so <Z_w> factorizes over the XOR support:
//      t_j = cos(v_j + rx_j)
//      qout[0] = t1*...*t7 ; qout[w] = t0*...*tw (w>=1)
//  - out = qout @ Wc^T + bc
//
// Pipeline: GEMM1(f32->bf16 on the fly, out bf16 V in ws, 4 MB)
//           -> quantum elementwise in place on V
//           -> GEMM2(V bf16 x Wc f32->bf16, +bias, out f32)

#define BN 2048
#define EN 1024

typedef short s16x8 __attribute__((ext_vector_type(8)));
typedef float f32x4 __attribute__((ext_vector_type(4)));

union Frag { s16x8 v; __hip_bfloat16 h[8]; };

__device__ inline s16x8 ld_frag_f32(const float* __restrict__ p) {
    f32x4 lo = *(const f32x4*)p;
    f32x4 hi = *(const f32x4*)(p + 4);
    Frag u;
    #pragma unroll
    for (int j = 0; j < 4; ++j) u.h[j] = __float2bfloat16(lo[j]);
    #pragma unroll
    for (int j = 0; j < 4; ++j) u.h[4 + j] = __float2bfloat16(hi[j]);
    return u.v;
}

// mfma_f32_16x16x32_bf16 layouts (HW-verified per guide):
//   A frag: A[m = lane&15][k = (lane>>4)*8 + j]  (8 contiguous elems)
//   B frag: W[n = lane&15][k = (lane>>4)*8 + j]
//   C/D:    col = lane&15, row = (lane>>4)*4 + reg
// block = 256 threads (4 waves), block tile 64x64, wave tile 32x32 (2x2 MFMAs)

// GEMM1: V[m,n] = sum_k x[m,k] * wv[n,k]; x,wv f32; V bf16.
__global__ __launch_bounds__(256) void gemm1_kernel(
        const float* __restrict__ A,
        const float* __restrict__ W,
        __hip_bfloat16* __restrict__ C)
{
    const int wave = threadIdx.x >> 6;
    const int lane = threadIdx.x & 63;
    const int m0 = blockIdx.x * 64 + (wave & 1) * 32;
    const int n0 = blockIdx.y * 64 + (wave >> 1) * 32;
    const int l15 = lane & 15;
    const int lq  = lane >> 4;

    const float* A0 = A + (size_t)(m0 + l15) * EN + lq * 8;
    const float* A1 = A0 + 16 * EN;
    const float* B0 = W + (size_t)(n0 + l15) * EN + lq * 8;
    const float* B1 = B0 + 16 * EN;

    f32x4 acc00 = {0.f, 0.f, 0.f, 0.f};
    f32x4 acc01 = acc00, acc10 = acc00, acc11 = acc00;

    for (int k = 0; k < EN; k += 32) {
        s16x8 a0 = ld_frag_f32(A0 + k);
        s16x8 a1 = ld_frag_f32(A1 + k);
        s16x8 b0 = ld_frag_f32(B0 + k);
        s16x8 b1 = ld_frag_f32(B1 + k);
        acc00 = __builtin_amdgcn_mfma_f32_16x16x32_bf16(a0, b0, acc00, 0, 0, 0);
        acc01 = __builtin_amdgcn_mfma_f32_16x16x32_bf16(a0, b1, acc01, 0, 0, 0);
        acc10 = __builtin_amdgcn_mfma_f32_16x16x32_bf16(a1, b0, acc10, 0, 0, 0);
        acc11 = __builtin_amdgcn_mfma_f32_16x16x32_bf16(a1, b1, acc11, 0, 0, 0);
    }

    f32x4 accs[2][2] = {{acc00, acc01}, {acc10, acc11}};
    #pragma unroll
    for (int mi = 0; mi < 2; ++mi)
        #pragma unroll
        for (int ni = 0; ni < 2; ++ni) {
            const int col = n0 + ni * 16 + l15;
            #pragma unroll
            for (int r = 0; r < 4; ++r) {
                const int row = m0 + mi * 16 + lq * 4 + r;
                C[(size_t)row * EN + col] = __float2bfloat16(accs[mi][ni][r]);
            }
        }
}

// GEMM2: out[m,n] = sum_k Q[m,k] * wc[n,k] + bc[n]; Q bf16; wc,bc,out f32.
__global__ __launch_bounds__(256) void gemm2_kernel(
        const __hip_bfloat16* __restrict__ A,
        const float* __restrict__ W,
        const float* __restrict__ bias,
        float* __restrict__ C)
{
    const int wave = threadIdx.x >> 6;
    const int lane = threadIdx.x & 63;
    const int m0 = blockIdx.x * 64 + (wave & 1) * 32;
    const int n0 = blockIdx.y * 64 + (wave >> 1) * 32;
    const int l15 = lane & 15;
    const int lq  = lane >> 4;

    const __hip_bfloat16* A0 = A + (size_t)(m0 + l15) * EN + lq * 8;
    const __hip_bfloat16* A1 = A0 + 16 * EN;
    const float* B0 = W + (size_t)(n0 + l15) * EN + lq * 8;
    const float* B1 = B0 + 16 * EN;

    f32x4 acc00 = {0.f, 0.f, 0.f, 0.f};
    f32x4 acc01 = acc00, acc10 = acc00, acc11 = acc00;

    for (int k = 0; k < EN; k += 32) {
        s16x8 a0 = *(const s16x8*)(A0 + k);
        s16x8 a1 = *(const s16x8*)(A1 + k);
        s16x8 b0 = ld_frag_f32(B0 + k);
        s16x8 b1 = ld_frag_f32(B1 + k);
        acc00 = __builtin_amdgcn_mfma_f32_16x16x32_bf16(a0, b0, acc00, 0, 0, 0);
        acc01 = __builtin_amdgcn_mfma_f32_16x16x32_bf16(a0, b1, acc01, 0, 0, 0);
        acc10 = __builtin_amdgcn_mfma_f32_16x16x32_bf16(a1, b0, acc10, 0, 0, 0);
        acc11 = __builtin_amdgcn_mfma_f32_16x16x32_bf16(a1, b1, acc11, 0, 0, 0);
    }

    f32x4 accs[2][2] = {{acc00, acc01}, {acc10, acc11}};
    #pragma unroll
    for (int mi = 0; mi < 2; ++mi)
        #pragma unroll
        for (int ni = 0; ni < 2; ++ni) {
            const int col = n0 + ni * 16 + l15;
            const float b = bias[col];
            #pragma unroll
            for (int r = 0; r < 4; ++r) {
                const int row = m0 + mi * 16 + lq * 4 + r;
                C[(size_t)row * EN + col] = accs[mi][ni][r] + b;
            }
        }
}

// One thread per (b,h) group of 8 angles; in-place on V (bf16).
__global__ __launch_bounds__(256) void quantum_kernel(
        __hip_bfloat16* __restrict__ V,
        const float* __restrict__ rx)
{
    const int g = blockIdx.x * 256 + threadIdx.x;   // exact grid: BN*EN/8 threads
    Frag in;
    in.v = *(const s16x8*)(V + (size_t)g * 8);
    float t[8];
    #pragma unroll
    for (int j = 0; j < 8; ++j)
        t[j] = cosf(__bfloat162float(in.h[j]) + rx[j]);

    Frag out;
    float suf = t[1];
    #pragma unroll
    for (int j = 2; j < 8; ++j) suf *= t[j];
    out.h[0] = __float2bfloat16(suf);
    float p = t[0];
    #pragma unroll
    for (int j = 1; j < 8; ++j) { p *= t[j]; out.h[j] = __float2bfloat16(p); }

    *(s16x8*)(V + (size_t)g * 8) = out.v;
}

extern "C" void kernel_launch(void* const* d_in, const int* in_sizes, int n_in,
                              void* d_out, int out_size, void* d_ws, size_t ws_size,
                              hipStream_t stream)
{
    // setup_inputs order: x, wq, wk, wv, wc, bc, rx_params (wq/wk unused: S==1)
    const float* x  = (const float*)d_in[0];
    const float* wv = (const float*)d_in[3];
    const float* wc = (const float*)d_in[4];
    const float* bc = (const float*)d_in[5];
    const float* rx = (const float*)d_in[6];
    float* out = (float*)d_out;

    __hip_bfloat16* V = (__hip_bfloat16*)d_ws;   // BN*EN bf16 = 4 MB scratch

    dim3 grid(BN / 64, EN / 64);                 // 32 x 16 = 512 blocks
    gemm1_kernel<<<grid, 256, 0, stream>>>(x, wv, V);
    quantum_kernel<<<(BN * EN / 8) / 256, 256, 0, stream>>>(V, rx);
    gemm2_kernel<<<grid, 256, 0, stream>>>(V, wc, bc, out);
}